// Round 4
// baseline (12940.997 us; speedup 1.0000x reference)
//
#include <hip/hip_runtime.h>
#include <math.h>

#define BB 8
#define NN 2048
#define KK 10
#define NSTRIP 8
#define EPSF 1e-5f
#define NEG_SLOPE 0.2f

// ---------------- xx[n] = sum_c x[n,c]^2 ----------------
__global__ void xx_kernel(const float* __restrict__ x, float* __restrict__ xx, int C) {
    int i = blockIdx.x * blockDim.x + threadIdx.x;
    if (i >= BB * NN) return;
    const float* row = x + (size_t)i * C;
    float s = 0.f;
    for (int c = 0; c < C; ++c) { float v = row[c]; s = fmaf(v, v, s); }
    xx[i] = s;
}

// ---------------- fused dist GEMM + top-10 (per j-strip) ----------------
// Block: 64 rows (i-tile) x 256 cols (j-strip = 4 j-tiles).
// LDS: union layout — ds (64x68 scan buffer) ALIASES As+Bs (k-loop tiles).
// Timeline per tile: [stage As/Bs, sync, fma, sync]*chunks -> write ds ->
// sync -> scan(ds) -> sync(protects ds from next tile's staging). 17408 B
// total -> LDS no longer caps occupancy; launch_bounds(256,8) caps VGPR=64
// (HW quantum halves waves at >64 VGPRs, so 80 was costing half the waves).
// NOTE: FMA chain (k-chunk ascending, kk ascending) and the transform
// 2*acc - xi - xj are bit-identical to the original dist_gemm_kernel --
// numerics feed neighbor ordering; do not reorder.
// Top-k: 4 threads/row, each owns 16 cols of each 64-wide tile. UNSORTED
// top-10 with tracked worst slot (branchless, static indices); entry rule
// (v > vmin) || (v==vmin && j < jmin) == jax.lax.top_k tie order. Sorted
// once at the end (static 45-comparator bubble network), then 4-lane shfl
// pop-merge -> per-strip partial top-10 in pv/pj.
__global__ __launch_bounds__(256, 8) void dist_topk_kernel(
    const float* __restrict__ x, const float* __restrict__ xx,
    float* __restrict__ pv, int* __restrict__ pj, int C) {
    __shared__ float smem[4352];                    // 17408 B union
    float (*As)[68] = (float(*)[68])smem;           // [16][68]
    float (*Bs)[68] = (float(*)[68])(smem + 1088);  // [16][68]
    float (*ds)[68] = (float(*)[68])smem;           // [64][68] aliases As+Bs
    int b = blockIdx.y, strip = blockIdx.z;
    int i0 = blockIdx.x << 6;
    const float* xb = x + (size_t)b * NN * C;
    const float* xxb = xx + (size_t)b * NN;
    int tid = threadIdx.x;
    int tx = tid & 15, ty = tid >> 4;
    int vr = tid & 63, vq = tid >> 6;   // vectorized-staging mapping

    float4 xi4 = *(const float4*)&xxb[i0 + (ty << 2)];
    float xi[4] = {xi4.x, xi4.y, xi4.z, xi4.w};

    // unsorted per-thread top-10 + tracked worst entry
    float tv[KK]; int tj[KK];
    #pragma unroll
    for (int q = 0; q < KK; ++q) { tv[q] = -INFINITY; tj[q] = 0x7fffffff; }
    float vmin = -INFINITY; int jmin = 0x7fffffff; int smin = 0;
    int rrow = tid >> 2, seg = tid & 3;

    for (int jc = 0; jc < 4; ++jc) {
        int j0 = (strip << 8) + (jc << 6);
        float acc[4][4] = {};
        for (int k0 = 0; k0 < C; k0 += 16) {
            if (C >= 16) {
                // one float4 per thread per matrix (C%16==0 -> aligned, no bounds)
                const float4 a4g = *(const float4*)&xb[(size_t)(i0 + vr) * C + k0 + (vq << 2)];
                const float4 b4g = *(const float4*)&xb[(size_t)(j0 + vr) * C + k0 + (vq << 2)];
                int c0 = vq << 2;
                As[c0 + 0][vr] = a4g.x; As[c0 + 1][vr] = a4g.y;
                As[c0 + 2][vr] = a4g.z; As[c0 + 3][vr] = a4g.w;
                Bs[c0 + 0][vr] = b4g.x; Bs[c0 + 1][vr] = b4g.y;
                Bs[c0 + 2][vr] = b4g.z; Bs[c0 + 3][vr] = b4g.w;
            } else {
                // scalar fallback (C=5), bit-identical zero padding
                #pragma unroll
                for (int l = tid; l < 1024; l += 256) {
                    int r = l >> 4, c = l & 15;
                    int kc = k0 + c;
                    As[c][r] = (kc < C) ? xb[(size_t)(i0 + r) * C + kc] : 0.f;
                    Bs[c][r] = (kc < C) ? xb[(size_t)(j0 + r) * C + kc] : 0.f;
                }
            }
            __syncthreads();
            #pragma unroll
            for (int kk = 0; kk < 16; ++kk) {
                float4 a4 = *(const float4*)&As[kk][ty << 2];
                float4 b4 = *(const float4*)&Bs[kk][tx << 2];
                float a[4] = {a4.x, a4.y, a4.z, a4.w};
                float bv[4] = {b4.x, b4.y, b4.z, b4.w};
                #pragma unroll
                for (int u = 0; u < 4; ++u)
                    #pragma unroll
                    for (int v = 0; v < 4; ++v)
                        acc[u][v] = fmaf(a[u], bv[v], acc[u][v]);
            }
            __syncthreads();
        }
        // transform + stage tile into ds (overwrites As/Bs -- all reads done)
        float4 xj4 = *(const float4*)&xxb[j0 + (tx << 2)];
        float xj[4] = {xj4.x, xj4.y, xj4.z, xj4.w};
        #pragma unroll
        for (int u = 0; u < 4; ++u) {
            float4 o;
            o.x = 2.f * acc[u][0] - xi[u] - xj[0];
            o.y = 2.f * acc[u][1] - xi[u] - xj[1];
            o.z = 2.f * acc[u][2] - xi[u] - xj[2];
            o.w = 2.f * acc[u][3] - xi[u] - xj[3];
            *(float4*)&ds[(ty << 2) + u][tx << 2] = o;
        }
        __syncthreads();
        // scan: thread owns cols [seg*16, seg*16+16) of row rrow
        int jb = j0 + (seg << 4);
        #pragma unroll
        for (int q = 0; q < 4; ++q) {
            float4 f = *(const float4*)&ds[rrow][(seg << 4) + (q << 2)];
            float m4 = fmaxf(fmaxf(f.x, f.y), fmaxf(f.z, f.w));
            if (m4 >= vmin) {   // group filter: strict-less can never enter
                float fv4[4] = {f.x, f.y, f.z, f.w};
                #pragma unroll
                for (int e = 0; e < 4; ++e) {
                    float v = fv4[e]; int j = jb + (q << 2) + e;
                    bool ins = (v > vmin) || (v == vmin && j < jmin);
                    if (ins) {
                        #pragma unroll
                        for (int s = 0; s < KK; ++s) {
                            bool hit = (s == smin);
                            tv[s] = hit ? v : tv[s];
                            tj[s] = hit ? j : tj[s];
                        }
                        vmin = tv[0]; jmin = tj[0]; smin = 0;
                        #pragma unroll
                        for (int s = 1; s < KK; ++s) {
                            bool worse = (tv[s] < vmin) ||
                                         (tv[s] == vmin && tj[s] > jmin);
                            vmin = worse ? tv[s] : vmin;
                            jmin = worse ? tj[s] : jmin;
                            smin = worse ? s : smin;
                        }
                    }
                }
            }
        }
        __syncthreads();   // protect ds before next tile's As/Bs staging
    }

    // sort the 10 entries desc by (v, then j asc): static bubble network
    #pragma unroll
    for (int p = 0; p < KK - 1; ++p) {
        #pragma unroll
        for (int s = 1; s < KK - p; ++s) {
            bool sw = (tv[s] > tv[s - 1]) ||
                      (tv[s] == tv[s - 1] && tj[s] < tj[s - 1]);
            float va = sw ? tv[s] : tv[s - 1];
            float vb = sw ? tv[s - 1] : tv[s];
            int ja = sw ? tj[s] : tj[s - 1];
            int jb2 = sw ? tj[s - 1] : tj[s];
            tv[s - 1] = va; tv[s] = vb;
            tj[s - 1] = ja; tj[s] = jb2;
        }
    }

    // merge 4 lanes (one row) -> partial top-10 for this strip
    size_t prow = ((size_t)strip * BB * NN) + (size_t)b * NN + i0 + rrow;
    float* pvrow = pv + prow * KK;
    int* pjrow = pj + prow * KK;
    for (int r = 0; r < KK; ++r) {
        float bv = tv[0]; int bj = tj[0];
        float ov = __shfl_xor(bv, 1); int oj = __shfl_xor(bj, 1);
        if (ov > bv || (ov == bv && oj < bj)) { bv = ov; bj = oj; }
        ov = __shfl_xor(bv, 2); oj = __shfl_xor(bj, 2);
        if (ov > bv || (ov == bv && oj < bj)) { bv = ov; bj = oj; }
        if (seg == 0) { pvrow[r] = bv; pjrow[r] = bj; }
        if (tj[0] == bj) {   // unique j per (row,strip): exactly one lane pops
            #pragma unroll
            for (int q = 0; q < KK - 1; ++q) { tv[q] = tv[q + 1]; tj[q] = tj[q + 1]; }
            tv[KK - 1] = -INFINITY; tj[KK - 1] = 0x7fffffff;
        }
    }
}

// ---------------- merge NSTRIP per-strip sorted top-10 lists ----------------
// Strips cover ascending index ranges; tie-break on the actual index is
// exact jax.lax.top_k order.
__global__ void topk_merge_kernel(const float* __restrict__ pv,
                                  const int* __restrict__ pj,
                                  int* __restrict__ idxout) {
    int row = blockIdx.x * 256 + threadIdx.x;
    if (row >= BB * NN) return;
    int p[NSTRIP];
    #pragma unroll
    for (int s = 0; s < NSTRIP; ++s) p[s] = 0;
    int* out = idxout + (size_t)row * KK;
    #pragma unroll
    for (int r = 0; r < KK; ++r) {
        float bv = -INFINITY; int bj = 0x7fffffff; int bs = -1;
        #pragma unroll
        for (int s = 0; s < NSTRIP; ++s) {
            size_t base = ((size_t)s * BB * NN + row) * KK + p[s];
            float v = pv[base];
            int j = pj[base];
            if (v > bv || (v == bv && j < bj)) { bv = v; bj = j; bs = s; }
        }
        out[r] = bj;
        #pragma unroll
        for (int s = 0; s < NSTRIP; ++s) if (s == bs) ++p[s];
    }
}

// ---------------- y,z = X*W1^T, X*W2^T as one tiled GEMM ----------------
__global__ __launch_bounds__(256) void yz_gemm_kernel(
    const float* __restrict__ x, const float* __restrict__ w,
    float* __restrict__ y, float* __restrict__ z, int C, int co) {
    int n0 = blockIdx.y << 6;     // point tile
    int oc0 = blockIdx.x << 6;    // combined output-channel tile
    __shared__ float As[16][68], Bs[16][68];
    int tid = threadIdx.x;
    int tx = tid & 15, ty = tid >> 4;
    float acc[4][4] = {};
    for (int k0 = 0; k0 < C; k0 += 16) {
        #pragma unroll
        for (int l = tid; l < 1024; l += 256) {
            int r = l >> 4, c = l & 15;
            int kc = k0 + c;
            As[c][r] = (kc < C) ? x[(size_t)(n0 + r) * C + kc] : 0.f;
            float bvv = 0.f;
            if (kc < C) {
                int oc = oc0 + r;
                int wrow = (oc < co) ? oc : (oc - co);
                int wcol = (oc < co) ? kc : (C + kc);
                bvv = w[(size_t)wrow * 2 * C + wcol];
            }
            Bs[c][r] = bvv;
        }
        __syncthreads();
        #pragma unroll
        for (int kk = 0; kk < 16; ++kk) {
            float4 a4 = *(const float4*)&As[kk][ty << 2];
            float4 b4 = *(const float4*)&Bs[kk][tx << 2];
            float a[4] = {a4.x, a4.y, a4.z, a4.w};
            float bv[4] = {b4.x, b4.y, b4.z, b4.w};
            #pragma unroll
            for (int u = 0; u < 4; ++u)
                #pragma unroll
                for (int v = 0; v < 4; ++v)
                    acc[u][v] = fmaf(a[u], bv[v], acc[u][v]);
        }
        __syncthreads();
    }
    bool isY = (oc0 < co);
    float* dst = isY ? y : z;
    int c0 = isY ? oc0 : (oc0 - co);
    #pragma unroll
    for (int u = 0; u < 4; ++u) {
        int n = n0 + (ty << 2) + u;
        float4 o;
        o.x = acc[u][0]; o.y = acc[u][1]; o.z = acc[u][2]; o.w = acc[u][3];
        *(float4*)&dst[(size_t)n * co + c0 + (tx << 2)] = o;
    }
}

// ---------------- gather + max_k + BN + lrelu ----------------
__global__ void edge_apply_kernel(const float* __restrict__ y, const float* __restrict__ z,
    const int* __restrict__ idx, const float* __restrict__ g, const float* __restrict__ be,
    const float* __restrict__ rm, const float* __restrict__ rv,
    float* __restrict__ out, int co) {
    int n = blockIdx.x;   // global point id in [0, B*N)
    int o = threadIdx.x;
    int b = n >> 11;      // N = 2048
    __shared__ int sj[KK];
    if (o < KK) sj[o] = idx[(size_t)n * KK + o];
    __syncthreads();
    float yn = y[(size_t)n * co + o], zn = z[(size_t)n * co + o];
    float mx = -INFINITY, mn = INFINITY;
    #pragma unroll
    for (int j = 0; j < KK; ++j) {
        float v = y[((size_t)b * NN + sj[j]) * co + o];
        mx = fmaxf(mx, v);
        mn = fminf(mn, v);
    }
    float s = g[o] * rsqrtf(rv[o] + EPSF);
    float tt = be[o] - rm[o] * s;
    float ybest = (s >= 0.f) ? mx : mn;
    float h = fmaf(s, ybest - yn + zn, tt);
    out[(size_t)n * co + o] = (h >= 0.f) ? h : NEG_SLOPE * h;
}

// ---------------- global max over N of concat(x1..x4) ----------------
#define NSPLIT 32
__global__ void gmax_partial(const float* __restrict__ x1, const float* __restrict__ x2,
                             const float* __restrict__ x3, const float* __restrict__ x4,
                             float* __restrict__ part) {
    int ch = threadIdx.x;            // 0..511
    int split = blockIdx.x, b = blockIdx.y;
    int n0 = split * (NN / NSPLIT);
    float m = -INFINITY;
    for (int q = 0; q < NN / NSPLIT; ++q) {
        int n = b * NN + n0 + q;
        float v;
        if (ch < 64)       v = x1[(size_t)n * 64 + ch];
        else if (ch < 128) v = x2[(size_t)n * 64 + (ch - 64)];
        else if (ch < 256) v = x3[(size_t)n * 128 + (ch - 128)];
        else               v = x4[(size_t)n * 256 + (ch - 256)];
        m = fmaxf(m, v);
    }
    part[((size_t)split * BB + b) * 512 + ch] = m;
}

__global__ void gmax_final(const float* __restrict__ part, float* __restrict__ xg) {
    int ch = threadIdx.x, b = blockIdx.x;
    float m = -INFINITY;
    for (int s = 0; s < NSPLIT; ++s) m = fmaxf(m, part[((size_t)s * BB + b) * 512 + ch]);
    xg[(size_t)b * 512 + ch] = m;
}

// ---------------- final linear + BN + lrelu ----------------
__global__ void linear_kernel(const float* __restrict__ xg, const float* __restrict__ lw,
    const float* __restrict__ lb, const float* __restrict__ g5, const float* __restrict__ b5,
    const float* __restrict__ rm5, const float* __restrict__ rv5, float* __restrict__ out0) {
    int o = blockIdx.x * 256 + threadIdx.x;
    int b = blockIdx.y;
    __shared__ float xs[512];
    for (int l = threadIdx.x; l < 512; l += 256) xs[l] = xg[(size_t)b * 512 + l];
    __syncthreads();
    float acc = 0.f;
    const float* wr = lw + (size_t)o * 512;
    for (int c = 0; c < 512; ++c) acc = fmaf(xs[c], wr[c], acc);
    acc += lb[o];
    float s = g5[o] * rsqrtf(rv5[o] + EPSF);
    float h = fmaf(s, acc - rm5[o], b5[o]);
    out0[(size_t)b * 1024 + o] = (h >= 0.f) ? h : NEG_SLOPE * h;
}

// ---------------- x4 (B,N,256) -> out1 (B,256,N) ----------------
__global__ void transpose_kernel(const float* __restrict__ x4, float* __restrict__ out1) {
    __shared__ float tile[32][33];
    int b = blockIdx.z;
    int nb = blockIdx.x * 32, ob = blockIdx.y * 32;
    int tx = threadIdx.x, ty = threadIdx.y;  // (32, 8)
    #pragma unroll
    for (int r = 0; r < 4; ++r) {
        int o = ob + tx;
        int n = nb + ty + r * 8;
        tile[ty + r * 8][tx] = x4[((size_t)b * NN + n) * 256 + o];
    }
    __syncthreads();
    #pragma unroll
    for (int r = 0; r < 4; ++r) {
        int n = nb + tx;
        int o = ob + ty + r * 8;
        out1[((size_t)b * 256 + o) * NN + n] = tile[tx][ty + r * 8];
    }
}

extern "C" void kernel_launch(void* const* d_in, const int* in_sizes, int n_in,
                              void* d_out, int out_size, void* d_ws, size_t ws_size,
                              hipStream_t stream) {
    const float* x = (const float*)d_in[0];
    const float* lin_w = (const float*)d_in[21];
    const float* lin_b = (const float*)d_in[22];
    const float* g5 = (const float*)d_in[23];
    const float* b5 = (const float*)d_in[24];
    const float* rm5 = (const float*)d_in[25];
    const float* rv5 = (const float*)d_in[26];

    // ---- workspace bump allocation ----
    size_t off = 0;
    auto alloc = [&](size_t nbytes) {
        void* r = (char*)d_ws + off;
        off += (nbytes + 255) & ~(size_t)255;
        return r;
    };
    const size_t PTS = (size_t)BB * NN;
    float* xx   = (float*)alloc(PTS * 4);
    int*   idx  = (int*)  alloc(PTS * KK * 4);
    float* y    = (float*)alloc(PTS * 256 * 4);
    float* z    = (float*)alloc(PTS * 256 * 4);
    float* x1   = (float*)alloc(PTS * 64 * 4);
    float* x2   = (float*)alloc(PTS * 64 * 4);
    float* x3   = (float*)alloc(PTS * 128 * 4);
    float* x4   = (float*)alloc(PTS * 256 * 4);
    float* part = (float*)alloc((size_t)NSPLIT * BB * 512 * 4);
    float* xg   = (float*)alloc((size_t)BB * 512 * 4);
    float* pv   = (float*)alloc((size_t)NSTRIP * PTS * KK * 4);  // per-strip top-10 values
    int*   pjb  = (int*)  alloc((size_t)NSTRIP * PTS * KK * 4);  // per-strip top-10 indices

    const int CI[4] = {5, 64, 64, 128};
    const int CO[4] = {64, 64, 128, 256};
    const float* xin = x;
    float* xout[4] = {x1, x2, x3, x4};

    for (int l = 0; l < 4; ++l) {
        int C = CI[l], co = CO[l];
        const float* w  = (const float*)d_in[1 + l * 5 + 0];
        const float* g  = (const float*)d_in[1 + l * 5 + 1];
        const float* be = (const float*)d_in[1 + l * 5 + 2];
        const float* rm = (const float*)d_in[1 + l * 5 + 3];
        const float* rv = (const float*)d_in[1 + l * 5 + 4];

        xx_kernel<<<(BB * NN + 255) / 256, 256, 0, stream>>>(xin, xx, C);

        dist_topk_kernel<<<dim3(NN / 64, BB, NSTRIP), 256, 0, stream>>>(
            xin, xx, pv, pjb, C);
        topk_merge_kernel<<<(int)((PTS + 255) / 256), 256, 0, stream>>>(pv, pjb, idx);

        yz_gemm_kernel<<<dim3(2 * co / 64, (int)(PTS / 64)), 256, 0, stream>>>(
            xin, w, y, z, C, co);
        edge_apply_kernel<<<(int)PTS, co, 0, stream>>>(y, z, idx, g, be, rm, rv, xout[l], co);
        xin = xout[l];
    }

    gmax_partial<<<dim3(NSPLIT, BB), 512, 0, stream>>>(x1, x2, x3, x4, part);
    gmax_final<<<BB, 512, 0, stream>>>(part, xg);
    linear_kernel<<<dim3(1024 / 256, BB), 256, 0, stream>>>(
        xg, lin_w, lin_b, g5, b5, rm5, rv5, (float*)d_out);
    transpose_kernel<<<dim3(NN / 32, 256 / 32, BB), dim3(32, 8), 0, stream>>>(
        x4, (float*)d_out + (size_t)BB * 1024);
}

// Round 5
// 2359.520 us; speedup vs baseline: 5.4846x; 5.4846x over previous
//
#include <hip/hip_runtime.h>
#include <math.h>

#define BB 8
#define NN 2048
#define KK 10
#define NSTRIP 8
#define EPSF 1e-5f
#define NEG_SLOPE 0.2f

// ---------------- xx[n] = sum_c x[n,c]^2 ----------------
__global__ void xx_kernel(const float* __restrict__ x, float* __restrict__ xx, int C) {
    int i = blockIdx.x * blockDim.x + threadIdx.x;
    if (i >= BB * NN) return;
    const float* row = x + (size_t)i * C;
    float s = 0.f;
    for (int c = 0; c < C; ++c) { float v = row[c]; s = fmaf(v, v, s); }
    xx[i] = s;
}

// ---------------- fused dist GEMM + top-10 (per j-strip) ----------------
// Block: 64 rows (i-tile) x 256 cols (j-strip = 4 j-tiles).
// LDS: union layout — ds (64x68 scan buffer) ALIASES As+Bs (k-loop tiles).
// 17408 B total.
// launch_bounds(256, 6): VGPR target 512/6 ~= 85 >= natural ~80 -> NO
// spills. (256,8) forced VGPR=32 and spilled ~50 regs -> 7.8 GB scratch
// writes per dispatch, 12.9 ms total. Do not lower the target below the
// kernel's natural register demand.
// NOTE: FMA chain (k-chunk ascending, kk ascending) and the transform
// 2*acc - xi - xj are bit-identical to the original dist_gemm_kernel --
// numerics feed neighbor ordering; do not reorder.
// Top-k: 4 threads/row, each owns 16 cols of each 64-wide tile. UNSORTED
// top-10 with tracked worst slot (branchless, static indices); entry rule
// (v > vmin) || (v==vmin && j < jmin) == jax.lax.top_k tie order. Sorted
// once at the end (static 45-comparator bubble network), then 4-lane shfl
// pop-merge -> per-strip partial top-10 in pv/pj.
__global__ __launch_bounds__(256, 6) void dist_topk_kernel(
    const float* __restrict__ x, const float* __restrict__ xx,
    float* __restrict__ pv, int* __restrict__ pj, int C) {
    __shared__ float smem[4352];                    // 17408 B union
    float (*As)[68] = (float(*)[68])smem;           // [16][68]
    float (*Bs)[68] = (float(*)[68])(smem + 1088);  // [16][68]
    float (*ds)[68] = (float(*)[68])smem;           // [64][68] aliases As+Bs
    int b = blockIdx.y, strip = blockIdx.z;
    int i0 = blockIdx.x << 6;
    const float* xb = x + (size_t)b * NN * C;
    const float* xxb = xx + (size_t)b * NN;
    int tid = threadIdx.x;
    int tx = tid & 15, ty = tid >> 4;
    int vr = tid & 63, vq = tid >> 6;   // vectorized-staging mapping

    // unsorted per-thread top-10 + tracked worst entry
    float tv[KK]; int tj[KK];
    #pragma unroll
    for (int q = 0; q < KK; ++q) { tv[q] = -INFINITY; tj[q] = 0x7fffffff; }
    float vmin = -INFINITY; int jmin = 0x7fffffff; int smin = 0;
    int rrow = tid >> 2, seg = tid & 3;

    for (int jc = 0; jc < 4; ++jc) {
        int j0 = (strip << 8) + (jc << 6);
        float acc[4][4] = {};
        for (int k0 = 0; k0 < C; k0 += 16) {
            if (C >= 16) {
                // one float4 per thread per matrix (C%16==0 -> aligned, no bounds)
                const float4 a4g = *(const float4*)&xb[(size_t)(i0 + vr) * C + k0 + (vq << 2)];
                const float4 b4g = *(const float4*)&xb[(size_t)(j0 + vr) * C + k0 + (vq << 2)];
                int c0 = vq << 2;
                As[c0 + 0][vr] = a4g.x; As[c0 + 1][vr] = a4g.y;
                As[c0 + 2][vr] = a4g.z; As[c0 + 3][vr] = a4g.w;
                Bs[c0 + 0][vr] = b4g.x; Bs[c0 + 1][vr] = b4g.y;
                Bs[c0 + 2][vr] = b4g.z; Bs[c0 + 3][vr] = b4g.w;
            } else {
                // scalar fallback (C=5), bit-identical zero padding
                #pragma unroll
                for (int l = tid; l < 1024; l += 256) {
                    int r = l >> 4, c = l & 15;
                    int kc = k0 + c;
                    As[c][r] = (kc < C) ? xb[(size_t)(i0 + r) * C + kc] : 0.f;
                    Bs[c][r] = (kc < C) ? xb[(size_t)(j0 + r) * C + kc] : 0.f;
                }
            }
            __syncthreads();
            #pragma unroll
            for (int kk = 0; kk < 16; ++kk) {
                float4 a4 = *(const float4*)&As[kk][ty << 2];
                float4 b4 = *(const float4*)&Bs[kk][tx << 2];
                float a[4] = {a4.x, a4.y, a4.z, a4.w};
                float bv[4] = {b4.x, b4.y, b4.z, b4.w};
                #pragma unroll
                for (int u = 0; u < 4; ++u)
                    #pragma unroll
                    for (int v = 0; v < 4; ++v)
                        acc[u][v] = fmaf(a[u], bv[v], acc[u][v]);
            }
            __syncthreads();
        }
        // transform + stage tile into ds (overwrites As/Bs -- all reads done)
        float4 xi4 = *(const float4*)&xxb[i0 + (ty << 2)];   // reload per tile
        float xi[4] = {xi4.x, xi4.y, xi4.z, xi4.w};
        float4 xj4 = *(const float4*)&xxb[j0 + (tx << 2)];
        float xj[4] = {xj4.x, xj4.y, xj4.z, xj4.w};
        #pragma unroll
        for (int u = 0; u < 4; ++u) {
            float4 o;
            o.x = 2.f * acc[u][0] - xi[u] - xj[0];
            o.y = 2.f * acc[u][1] - xi[u] - xj[1];
            o.z = 2.f * acc[u][2] - xi[u] - xj[2];
            o.w = 2.f * acc[u][3] - xi[u] - xj[3];
            *(float4*)&ds[(ty << 2) + u][tx << 2] = o;
        }
        __syncthreads();
        // scan: thread owns cols [seg*16, seg*16+16) of row rrow
        int jb = j0 + (seg << 4);
        #pragma unroll
        for (int q = 0; q < 4; ++q) {
            float4 f = *(const float4*)&ds[rrow][(seg << 4) + (q << 2)];
            float m4 = fmaxf(fmaxf(f.x, f.y), fmaxf(f.z, f.w));
            if (m4 >= vmin) {   // group filter: strict-less can never enter
                float fv4[4] = {f.x, f.y, f.z, f.w};
                #pragma unroll
                for (int e = 0; e < 4; ++e) {
                    float v = fv4[e]; int j = jb + (q << 2) + e;
                    bool ins = (v > vmin) || (v == vmin && j < jmin);
                    if (ins) {
                        #pragma unroll
                        for (int s = 0; s < KK; ++s) {
                            bool hit = (s == smin);
                            tv[s] = hit ? v : tv[s];
                            tj[s] = hit ? j : tj[s];
                        }
                        vmin = tv[0]; jmin = tj[0]; smin = 0;
                        #pragma unroll
                        for (int s = 1; s < KK; ++s) {
                            bool worse = (tv[s] < vmin) ||
                                         (tv[s] == vmin && tj[s] > jmin);
                            vmin = worse ? tv[s] : vmin;
                            jmin = worse ? tj[s] : jmin;
                            smin = worse ? s : smin;
                        }
                    }
                }
            }
        }
        __syncthreads();   // protect ds before next tile's As/Bs staging
    }

    // sort the 10 entries desc by (v, then j asc): static bubble network
    #pragma unroll
    for (int p = 0; p < KK - 1; ++p) {
        #pragma unroll
        for (int s = 1; s < KK - p; ++s) {
            bool sw = (tv[s] > tv[s - 1]) ||
                      (tv[s] == tv[s - 1] && tj[s] < tj[s - 1]);
            float va = sw ? tv[s] : tv[s - 1];
            float vb = sw ? tv[s - 1] : tv[s];
            int ja = sw ? tj[s] : tj[s - 1];
            int jb2 = sw ? tj[s - 1] : tj[s];
            tv[s - 1] = va; tv[s] = vb;
            tj[s - 1] = ja; tj[s] = jb2;
        }
    }

    // merge 4 lanes (one row) -> partial top-10 for this strip
    size_t prow = ((size_t)strip * BB * NN) + (size_t)b * NN + i0 + rrow;
    float* pvrow = pv + prow * KK;
    int* pjrow = pj + prow * KK;
    for (int r = 0; r < KK; ++r) {
        float bv = tv[0]; int bj = tj[0];
        float ov = __shfl_xor(bv, 1); int oj = __shfl_xor(bj, 1);
        if (ov > bv || (ov == bv && oj < bj)) { bv = ov; bj = oj; }
        ov = __shfl_xor(bv, 2); oj = __shfl_xor(bj, 2);
        if (ov > bv || (ov == bv && oj < bj)) { bv = ov; bj = oj; }
        if (seg == 0) { pvrow[r] = bv; pjrow[r] = bj; }
        if (tj[0] == bj) {   // unique j per (row,strip): exactly one lane pops
            #pragma unroll
            for (int q = 0; q < KK - 1; ++q) { tv[q] = tv[q + 1]; tj[q] = tj[q + 1]; }
            tv[KK - 1] = -INFINITY; tj[KK - 1] = 0x7fffffff;
        }
    }
}

// ---------------- merge NSTRIP per-strip sorted top-10 lists ----------------
// Strips cover ascending index ranges; tie-break on the actual index is
// exact jax.lax.top_k order.
__global__ void topk_merge_kernel(const float* __restrict__ pv,
                                  const int* __restrict__ pj,
                                  int* __restrict__ idxout) {
    int row = blockIdx.x * 256 + threadIdx.x;
    if (row >= BB * NN) return;
    int p[NSTRIP];
    #pragma unroll
    for (int s = 0; s < NSTRIP; ++s) p[s] = 0;
    int* out = idxout + (size_t)row * KK;
    #pragma unroll
    for (int r = 0; r < KK; ++r) {
        float bv = -INFINITY; int bj = 0x7fffffff; int bs = -1;
        #pragma unroll
        for (int s = 0; s < NSTRIP; ++s) {
            size_t base = ((size_t)s * BB * NN + row) * KK + p[s];
            float v = pv[base];
            int j = pj[base];
            if (v > bv || (v == bv && j < bj)) { bv = v; bj = j; bs = s; }
        }
        out[r] = bj;
        #pragma unroll
        for (int s = 0; s < NSTRIP; ++s) if (s == bs) ++p[s];
    }
}

// ---------------- y,z = X*W1^T, X*W2^T as one tiled GEMM ----------------
__global__ __launch_bounds__(256) void yz_gemm_kernel(
    const float* __restrict__ x, const float* __restrict__ w,
    float* __restrict__ y, float* __restrict__ z, int C, int co) {
    int n0 = blockIdx.y << 6;     // point tile
    int oc0 = blockIdx.x << 6;    // combined output-channel tile
    __shared__ float As[16][68], Bs[16][68];
    int tid = threadIdx.x;
    int tx = tid & 15, ty = tid >> 4;
    float acc[4][4] = {};
    for (int k0 = 0; k0 < C; k0 += 16) {
        #pragma unroll
        for (int l = tid; l < 1024; l += 256) {
            int r = l >> 4, c = l & 15;
            int kc = k0 + c;
            As[c][r] = (kc < C) ? x[(size_t)(n0 + r) * C + kc] : 0.f;
            float bvv = 0.f;
            if (kc < C) {
                int oc = oc0 + r;
                int wrow = (oc < co) ? oc : (oc - co);
                int wcol = (oc < co) ? kc : (C + kc);
                bvv = w[(size_t)wrow * 2 * C + wcol];
            }
            Bs[c][r] = bvv;
        }
        __syncthreads();
        #pragma unroll
        for (int kk = 0; kk < 16; ++kk) {
            float4 a4 = *(const float4*)&As[kk][ty << 2];
            float4 b4 = *(const float4*)&Bs[kk][tx << 2];
            float a[4] = {a4.x, a4.y, a4.z, a4.w};
            float bv[4] = {b4.x, b4.y, b4.z, b4.w};
            #pragma unroll
            for (int u = 0; u < 4; ++u)
                #pragma unroll
                for (int v = 0; v < 4; ++v)
                    acc[u][v] = fmaf(a[u], bv[v], acc[u][v]);
        }
        __syncthreads();
    }
    bool isY = (oc0 < co);
    float* dst = isY ? y : z;
    int c0 = isY ? oc0 : (oc0 - co);
    #pragma unroll
    for (int u = 0; u < 4; ++u) {
        int n = n0 + (ty << 2) + u;
        float4 o;
        o.x = acc[u][0]; o.y = acc[u][1]; o.z = acc[u][2]; o.w = acc[u][3];
        *(float4*)&dst[(size_t)n * co + c0 + (tx << 2)] = o;
    }
}

// ---------------- gather + max_k + BN + lrelu ----------------
__global__ void edge_apply_kernel(const float* __restrict__ y, const float* __restrict__ z,
    const int* __restrict__ idx, const float* __restrict__ g, const float* __restrict__ be,
    const float* __restrict__ rm, const float* __restrict__ rv,
    float* __restrict__ out, int co) {
    int n = blockIdx.x;   // global point id in [0, B*N)
    int o = threadIdx.x;
    int b = n >> 11;      // N = 2048
    __shared__ int sj[KK];
    if (o < KK) sj[o] = idx[(size_t)n * KK + o];
    __syncthreads();
    float yn = y[(size_t)n * co + o], zn = z[(size_t)n * co + o];
    float mx = -INFINITY, mn = INFINITY;
    #pragma unroll
    for (int j = 0; j < KK; ++j) {
        float v = y[((size_t)b * NN + sj[j]) * co + o];
        mx = fmaxf(mx, v);
        mn = fminf(mn, v);
    }
    float s = g[o] * rsqrtf(rv[o] + EPSF);
    float tt = be[o] - rm[o] * s;
    float ybest = (s >= 0.f) ? mx : mn;
    float h = fmaf(s, ybest - yn + zn, tt);
    out[(size_t)n * co + o] = (h >= 0.f) ? h : NEG_SLOPE * h;
}

// ---------------- global max over N of concat(x1..x4) ----------------
#define NSPLIT 32
__global__ void gmax_partial(const float* __restrict__ x1, const float* __restrict__ x2,
                             const float* __restrict__ x3, const float* __restrict__ x4,
                             float* __restrict__ part) {
    int ch = threadIdx.x;            // 0..511
    int split = blockIdx.x, b = blockIdx.y;
    int n0 = split * (NN / NSPLIT);
    float m = -INFINITY;
    for (int q = 0; q < NN / NSPLIT; ++q) {
        int n = b * NN + n0 + q;
        float v;
        if (ch < 64)       v = x1[(size_t)n * 64 + ch];
        else if (ch < 128) v = x2[(size_t)n * 64 + (ch - 64)];
        else if (ch < 256) v = x3[(size_t)n * 128 + (ch - 128)];
        else               v = x4[(size_t)n * 256 + (ch - 256)];
        m = fmaxf(m, v);
    }
    part[((size_t)split * BB + b) * 512 + ch] = m;
}

__global__ void gmax_final(const float* __restrict__ part, float* __restrict__ xg) {
    int ch = threadIdx.x, b = blockIdx.x;
    float m = -INFINITY;
    for (int s = 0; s < NSPLIT; ++s) m = fmaxf(m, part[((size_t)s * BB + b) * 512 + ch]);
    xg[(size_t)b * 512 + ch] = m;
}

// ---------------- final linear + BN + lrelu ----------------
__global__ void linear_kernel(const float* __restrict__ xg, const float* __restrict__ lw,
    const float* __restrict__ lb, const float* __restrict__ g5, const float* __restrict__ b5,
    const float* __restrict__ rm5, const float* __restrict__ rv5, float* __restrict__ out0) {
    int o = blockIdx.x * 256 + threadIdx.x;
    int b = blockIdx.y;
    __shared__ float xs[512];
    for (int l = threadIdx.x; l < 512; l += 256) xs[l] = xg[(size_t)b * 512 + l];
    __syncthreads();
    float acc = 0.f;
    const float* wr = lw + (size_t)o * 512;
    for (int c = 0; c < 512; ++c) acc = fmaf(xs[c], wr[c], acc);
    acc += lb[o];
    float s = g5[o] * rsqrtf(rv5[o] + EPSF);
    float h = fmaf(s, acc - rm5[o], b5[o]);
    out0[(size_t)b * 1024 + o] = (h >= 0.f) ? h : NEG_SLOPE * h;
}

// ---------------- x4 (B,N,256) -> out1 (B,256,N) ----------------
__global__ void transpose_kernel(const float* __restrict__ x4, float* __restrict__ out1) {
    __shared__ float tile[32][33];
    int b = blockIdx.z;
    int nb = blockIdx.x * 32, ob = blockIdx.y * 32;
    int tx = threadIdx.x, ty = threadIdx.y;  // (32, 8)
    #pragma unroll
    for (int r = 0; r < 4; ++r) {
        int o = ob + tx;
        int n = nb + ty + r * 8;
        tile[ty + r * 8][tx] = x4[((size_t)b * NN + n) * 256 + o];
    }
    __syncthreads();
    #pragma unroll
    for (int r = 0; r < 4; ++r) {
        int n = nb + tx;
        int o = ob + ty + r * 8;
        out1[((size_t)b * 256 + o) * NN + n] = tile[tx][ty + r * 8];
    }
}

extern "C" void kernel_launch(void* const* d_in, const int* in_sizes, int n_in,
                              void* d_out, int out_size, void* d_ws, size_t ws_size,
                              hipStream_t stream) {
    const float* x = (const float*)d_in[0];
    const float* lin_w = (const float*)d_in[21];
    const float* lin_b = (const float*)d_in[22];
    const float* g5 = (const float*)d_in[23];
    const float* b5 = (const float*)d_in[24];
    const float* rm5 = (const float*)d_in[25];
    const float* rv5 = (const float*)d_in[26];

    // ---- workspace bump allocation ----
    size_t off = 0;
    auto alloc = [&](size_t nbytes) {
        void* r = (char*)d_ws + off;
        off += (nbytes + 255) & ~(size_t)255;
        return r;
    };
    const size_t PTS = (size_t)BB * NN;
    float* xx   = (float*)alloc(PTS * 4);
    int*   idx  = (int*)  alloc(PTS * KK * 4);
    float* y    = (float*)alloc(PTS * 256 * 4);
    float* z    = (float*)alloc(PTS * 256 * 4);
    float* x1   = (float*)alloc(PTS * 64 * 4);
    float* x2   = (float*)alloc(PTS * 64 * 4);
    float* x3   = (float*)alloc(PTS * 128 * 4);
    float* x4   = (float*)alloc(PTS * 256 * 4);
    float* part = (float*)alloc((size_t)NSPLIT * BB * 512 * 4);
    float* xg   = (float*)alloc((size_t)BB * 512 * 4);
    float* pv   = (float*)alloc((size_t)NSTRIP * PTS * KK * 4);  // per-strip top-10 values
    int*   pjb  = (int*)  alloc((size_t)NSTRIP * PTS * KK * 4);  // per-strip top-10 indices

    const int CI[4] = {5, 64, 64, 128};
    const int CO[4] = {64, 64, 128, 256};
    const float* xin = x;
    float* xout[4] = {x1, x2, x3, x4};

    for (int l = 0; l < 4; ++l) {
        int C = CI[l], co = CO[l];
        const float* w  = (const float*)d_in[1 + l * 5 + 0];
        const float* g  = (const float*)d_in[1 + l * 5 + 1];
        const float* be = (const float*)d_in[1 + l * 5 + 2];
        const float* rm = (const float*)d_in[1 + l * 5 + 3];
        const float* rv = (const float*)d_in[1 + l * 5 + 4];

        xx_kernel<<<(BB * NN + 255) / 256, 256, 0, stream>>>(xin, xx, C);

        dist_topk_kernel<<<dim3(NN / 64, BB, NSTRIP), 256, 0, stream>>>(
            xin, xx, pv, pjb, C);
        topk_merge_kernel<<<(int)((PTS + 255) / 256), 256, 0, stream>>>(pv, pjb, idx);

        yz_gemm_kernel<<<dim3(2 * co / 64, (int)(PTS / 64)), 256, 0, stream>>>(
            xin, w, y, z, C, co);
        edge_apply_kernel<<<(int)PTS, co, 0, stream>>>(y, z, idx, g, be, rm, rv, xout[l], co);
        xin = xout[l];
    }

    gmax_partial<<<dim3(NSPLIT, BB), 512, 0, stream>>>(x1, x2, x3, x4, part);
    gmax_final<<<BB, 512, 0, stream>>>(part, xg);
    linear_kernel<<<dim3(1024 / 256, BB), 256, 0, stream>>>(
        xg, lin_w, lin_b, g5, b5, rm5, rv5, (float*)d_out);
    transpose_kernel<<<dim3(NN / 32, 256 / 32, BB), dim3(32, 8), 0, stream>>>(
        x4, (float*)d_out + (size_t)BB * 1024);
}

// Round 6
// 1095.425 us; speedup vs baseline: 11.8137x; 2.1540x over previous
//
#include <hip/hip_runtime.h>
#include <math.h>

#define BB 8
#define NN 2048
#define KK 10
#define NSTRIP 8
#define EPSF 1e-5f
#define NEG_SLOPE 0.2f

// ---------------- xx[n] = sum_c x[n,c]^2 ----------------
__global__ void xx_kernel(const float* __restrict__ x, float* __restrict__ xx, int C) {
    int i = blockIdx.x * blockDim.x + threadIdx.x;
    if (i >= BB * NN) return;
    const float* row = x + (size_t)i * C;
    float s = 0.f;
    for (int c = 0; c < C; ++c) { float v = row[c]; s = fmaf(v, v, s); }
    xx[i] = s;
}

// ---------------- fused dist GEMM + top-10 (per j-strip) ----------------
// Block: 64 rows (i-tile) x 256 cols (j-strip = 4 j-tiles). LDS union:
// ds (64x68 scan buffer) aliases As+Bs (k-loop tiles); 17408 B total.
// REGISTER DIET (goal: natural VGPR <= 64 so waves/SIMD = 8, not 4):
//  - sorted-insert top-10: list always sorted desc by (v, j asc on ties);
//    worst entry IS the tail -> no vmin/jmin/smin regs, no final sort net.
//  - indices packed as u16 pairs: tjp[5] instead of tj[10] (j <= 2047,
//    sentinel 0xFFFF). All accesses statically unrolled.
//  - template<C>: literal strides, if constexpr staging, unroll 1 on
//    outer loops to forbid unroll-driven register growth.
// DO NOT add __launch_bounds__ waves hints or amdgpu_num_vgpr: measured
// (256,8)->VGPR32 and (256,6)->VGPR40, both with GB-scale scratch spills.
// NOTE: FMA chain (k-chunk ascending, kk ascending) and the transform
// 2*acc - xi - xj are bit-identical to the original dist_gemm_kernel --
// numerics feed neighbor ordering; do not reorder.
template<int C>
__global__ __launch_bounds__(256) void dist_topk_kernel(
    const float* __restrict__ x, const float* __restrict__ xx,
    float* __restrict__ pv, int* __restrict__ pj) {
    __shared__ float smem[4352];                    // 17408 B union
    float (*As)[68] = (float(*)[68])smem;           // [16][68]
    float (*Bs)[68] = (float(*)[68])(smem + 1088);  // [16][68]
    float (*ds)[68] = (float(*)[68])smem;           // [64][68] aliases As+Bs
    int b = blockIdx.y, strip = blockIdx.z;
    int i0 = blockIdx.x << 6;
    const float* xb = x + (size_t)b * NN * C;
    const float* xxb = xx + (size_t)b * NN;
    int tid = threadIdx.x;
    int tx = tid & 15, ty = tid >> 4;
    int vr = tid & 63, vq = tid >> 6;   // vectorized-staging mapping

    // sorted per-thread top-10: tv desc (ties j asc); tj packed u16 pairs
    float tv[KK];
    unsigned tjp[5];
    #pragma unroll
    for (int q = 0; q < KK; ++q) tv[q] = -INFINITY;
    #pragma unroll
    for (int p = 0; p < 5; ++p) tjp[p] = 0xFFFFFFFFu;
    int rrow = tid >> 2, seg = tid & 3;

    #pragma unroll 1
    for (int jc = 0; jc < 4; ++jc) {
        int j0 = (strip << 8) + (jc << 6);
        float acc[4][4] = {};
        #pragma unroll 1
        for (int k0 = 0; k0 < C; k0 += 16) {
            if constexpr (C >= 16) {
                // one float4 per thread per matrix (C%16==0 -> aligned)
                const float4 a4g = *(const float4*)&xb[(i0 + vr) * C + k0 + (vq << 2)];
                const float4 b4g = *(const float4*)&xb[(j0 + vr) * C + k0 + (vq << 2)];
                int c0 = vq << 2;
                As[c0 + 0][vr] = a4g.x; As[c0 + 1][vr] = a4g.y;
                As[c0 + 2][vr] = a4g.z; As[c0 + 3][vr] = a4g.w;
                Bs[c0 + 0][vr] = b4g.x; Bs[c0 + 1][vr] = b4g.y;
                Bs[c0 + 2][vr] = b4g.z; Bs[c0 + 3][vr] = b4g.w;
            } else {
                // scalar path (C=5), bit-identical zero padding
                #pragma unroll
                for (int l = tid; l < 1024; l += 256) {
                    int r = l >> 4, c = l & 15;
                    int kc = k0 + c;
                    As[c][r] = (kc < C) ? xb[(i0 + r) * C + kc] : 0.f;
                    Bs[c][r] = (kc < C) ? xb[(j0 + r) * C + kc] : 0.f;
                }
            }
            __syncthreads();
            #pragma unroll
            for (int kk = 0; kk < 16; ++kk) {
                float4 a4 = *(const float4*)&As[kk][ty << 2];
                float4 b4 = *(const float4*)&Bs[kk][tx << 2];
                float a[4] = {a4.x, a4.y, a4.z, a4.w};
                float bv[4] = {b4.x, b4.y, b4.z, b4.w};
                #pragma unroll
                for (int u = 0; u < 4; ++u)
                    #pragma unroll
                    for (int v = 0; v < 4; ++v)
                        acc[u][v] = fmaf(a[u], bv[v], acc[u][v]);
            }
            __syncthreads();
        }
        // transform + stage tile into ds (overwrites As/Bs -- reads done)
        float4 xi4 = *(const float4*)&xxb[i0 + (ty << 2)];
        float xi[4] = {xi4.x, xi4.y, xi4.z, xi4.w};
        float4 xj4 = *(const float4*)&xxb[j0 + (tx << 2)];
        float xj[4] = {xj4.x, xj4.y, xj4.z, xj4.w};
        #pragma unroll
        for (int u = 0; u < 4; ++u) {
            float4 o;
            o.x = 2.f * acc[u][0] - xi[u] - xj[0];
            o.y = 2.f * acc[u][1] - xi[u] - xj[1];
            o.z = 2.f * acc[u][2] - xi[u] - xj[2];
            o.w = 2.f * acc[u][3] - xi[u] - xj[3];
            *(float4*)&ds[(ty << 2) + u][tx << 2] = o;
        }
        __syncthreads();
        // scan: thread owns cols [seg*16, seg*16+16) of row rrow
        int jb = j0 + (seg << 4);
        #pragma unroll
        for (int q = 0; q < 4; ++q) {
            float4 f = *(const float4*)&ds[rrow][(seg << 4) + (q << 2)];
            float m4 = fmaxf(fmaxf(f.x, f.y), fmaxf(f.z, f.w));
            if (m4 >= tv[KK - 1]) {   // group filter: strict-less never enters
                float fv4[4] = {f.x, f.y, f.z, f.w};
                #pragma unroll
                for (int e = 0; e < 4; ++e) {
                    float v = fv4[e];
                    unsigned j = (unsigned)(jb + (q << 2) + e);
                    unsigned t9 = tjp[4] >> 16;
                    bool ins = (v > tv[KK - 1]) || (v == tv[KK - 1] && j < t9);
                    if (ins) {
                        unsigned t[KK];
                        #pragma unroll
                        for (int s = 0; s < KK; ++s)
                            t[s] = (tjp[s >> 1] >> ((s & 1) << 4)) & 0xFFFFu;
                        bool bt[KK];
                        #pragma unroll
                        for (int s = 0; s < KK; ++s)
                            bt[s] = (v > tv[s]) || (v == tv[s] && j < t[s]);
                        float ntv[KK]; unsigned nt[KK];
                        ntv[0] = bt[0] ? v : tv[0];
                        nt[0]  = bt[0] ? j : t[0];
                        #pragma unroll
                        for (int s = 1; s < KK; ++s) {
                            ntv[s] = bt[s] ? (bt[s - 1] ? tv[s - 1] : v) : tv[s];
                            nt[s]  = bt[s] ? (bt[s - 1] ? t[s - 1] : j) : t[s];
                        }
                        #pragma unroll
                        for (int s = 0; s < KK; ++s) tv[s] = ntv[s];
                        #pragma unroll
                        for (int p = 0; p < 5; ++p)
                            tjp[p] = nt[2 * p] | (nt[2 * p + 1] << 16);
                    }
                }
            }
        }
        __syncthreads();   // protect ds before next tile's As/Bs staging
    }

    // merge 4 lanes (one row) -> partial top-10 for this strip
    size_t prow = ((size_t)strip * BB * NN) + (size_t)b * NN + i0 + rrow;
    float* pvrow = pv + prow * KK;
    int* pjrow = pj + prow * KK;
    for (int r = 0; r < KK; ++r) {
        float bv = tv[0];
        unsigned bj = tjp[0] & 0xFFFFu;
        float ov = __shfl_xor(bv, 1);
        unsigned oj = (unsigned)__shfl_xor((int)bj, 1);
        if (ov > bv || (ov == bv && oj < bj)) { bv = ov; bj = oj; }
        ov = __shfl_xor(bv, 2);
        oj = (unsigned)__shfl_xor((int)bj, 2);
        if (ov > bv || (ov == bv && oj < bj)) { bv = ov; bj = oj; }
        if (seg == 0) { pvrow[r] = bv; pjrow[r] = (int)bj; }
        if ((tjp[0] & 0xFFFFu) == bj) {  // unique j per (row,strip): one lane pops
            #pragma unroll
            for (int s = 0; s < KK - 1; ++s) tv[s] = tv[s + 1];
            tv[KK - 1] = -INFINITY;
            #pragma unroll
            for (int p = 0; p < 4; ++p) tjp[p] = (tjp[p] >> 16) | (tjp[p + 1] << 16);
            tjp[4] = (tjp[4] >> 16) | 0xFFFF0000u;
        }
    }
}

// ---------------- merge NSTRIP per-strip sorted top-10 lists ----------------
// Strips cover ascending index ranges; tie-break on the actual index is
// exact jax.lax.top_k order.
__global__ void topk_merge_kernel(const float* __restrict__ pv,
                                  const int* __restrict__ pj,
                                  int* __restrict__ idxout) {
    int row = blockIdx.x * 256 + threadIdx.x;
    if (row >= BB * NN) return;
    int p[NSTRIP];
    #pragma unroll
    for (int s = 0; s < NSTRIP; ++s) p[s] = 0;
    int* out = idxout + (size_t)row * KK;
    #pragma unroll
    for (int r = 0; r < KK; ++r) {
        float bv = -INFINITY; int bj = 0x7fffffff; int bs = -1;
        #pragma unroll
        for (int s = 0; s < NSTRIP; ++s) {
            size_t base = ((size_t)s * BB * NN + row) * KK + p[s];
            float v = pv[base];
            int j = pj[base];
            if (v > bv || (v == bv && j < bj)) { bv = v; bj = j; bs = s; }
        }
        out[r] = bj;
        #pragma unroll
        for (int s = 0; s < NSTRIP; ++s) if (s == bs) ++p[s];
    }
}

// ---------------- y,z = X*W1^T, X*W2^T as one tiled GEMM ----------------
__global__ __launch_bounds__(256) void yz_gemm_kernel(
    const float* __restrict__ x, const float* __restrict__ w,
    float* __restrict__ y, float* __restrict__ z, int C, int co) {
    int n0 = blockIdx.y << 6;     // point tile
    int oc0 = blockIdx.x << 6;    // combined output-channel tile
    __shared__ float As[16][68], Bs[16][68];
    int tid = threadIdx.x;
    int tx = tid & 15, ty = tid >> 4;
    float acc[4][4] = {};
    for (int k0 = 0; k0 < C; k0 += 16) {
        #pragma unroll
        for (int l = tid; l < 1024; l += 256) {
            int r = l >> 4, c = l & 15;
            int kc = k0 + c;
            As[c][r] = (kc < C) ? x[(size_t)(n0 + r) * C + kc] : 0.f;
            float bvv = 0.f;
            if (kc < C) {
                int oc = oc0 + r;
                int wrow = (oc < co) ? oc : (oc - co);
                int wcol = (oc < co) ? kc : (C + kc);
                bvv = w[(size_t)wrow * 2 * C + wcol];
            }
            Bs[c][r] = bvv;
        }
        __syncthreads();
        #pragma unroll
        for (int kk = 0; kk < 16; ++kk) {
            float4 a4 = *(const float4*)&As[kk][ty << 2];
            float4 b4 = *(const float4*)&Bs[kk][tx << 2];
            float a[4] = {a4.x, a4.y, a4.z, a4.w};
            float bv[4] = {b4.x, b4.y, b4.z, b4.w};
            #pragma unroll
            for (int u = 0; u < 4; ++u)
                #pragma unroll
                for (int v = 0; v < 4; ++v)
                    acc[u][v] = fmaf(a[u], bv[v], acc[u][v]);
        }
        __syncthreads();
    }
    bool isY = (oc0 < co);
    float* dst = isY ? y : z;
    int c0 = isY ? oc0 : (oc0 - co);
    #pragma unroll
    for (int u = 0; u < 4; ++u) {
        int n = n0 + (ty << 2) + u;
        float4 o;
        o.x = acc[u][0]; o.y = acc[u][1]; o.z = acc[u][2]; o.w = acc[u][3];
        *(float4*)&dst[(size_t)n * co + c0 + (tx << 2)] = o;
    }
}

// ---------------- gather + max_k + BN + lrelu ----------------
__global__ void edge_apply_kernel(const float* __restrict__ y, const float* __restrict__ z,
    const int* __restrict__ idx, const float* __restrict__ g, const float* __restrict__ be,
    const float* __restrict__ rm, const float* __restrict__ rv,
    float* __restrict__ out, int co) {
    int n = blockIdx.x;   // global point id in [0, B*N)
    int o = threadIdx.x;
    int b = n >> 11;      // N = 2048
    __shared__ int sj[KK];
    if (o < KK) sj[o] = idx[(size_t)n * KK + o];
    __syncthreads();
    float yn = y[(size_t)n * co + o], zn = z[(size_t)n * co + o];
    float mx = -INFINITY, mn = INFINITY;
    #pragma unroll
    for (int j = 0; j < KK; ++j) {
        float v = y[((size_t)b * NN + sj[j]) * co + o];
        mx = fmaxf(mx, v);
        mn = fminf(mn, v);
    }
    float s = g[o] * rsqrtf(rv[o] + EPSF);
    float tt = be[o] - rm[o] * s;
    float ybest = (s >= 0.f) ? mx : mn;
    float h = fmaf(s, ybest - yn + zn, tt);
    out[(size_t)n * co + o] = (h >= 0.f) ? h : NEG_SLOPE * h;
}

// ---------------- global max over N of concat(x1..x4) ----------------
#define NSPLIT 32
__global__ void gmax_partial(const float* __restrict__ x1, const float* __restrict__ x2,
                             const float* __restrict__ x3, const float* __restrict__ x4,
                             float* __restrict__ part) {
    int ch = threadIdx.x;            // 0..511
    int split = blockIdx.x, b = blockIdx.y;
    int n0 = split * (NN / NSPLIT);
    float m = -INFINITY;
    for (int q = 0; q < NN / NSPLIT; ++q) {
        int n = b * NN + n0 + q;
        float v;
        if (ch < 64)       v = x1[(size_t)n * 64 + ch];
        else if (ch < 128) v = x2[(size_t)n * 64 + (ch - 64)];
        else if (ch < 256) v = x3[(size_t)n * 128 + (ch - 128)];
        else               v = x4[(size_t)n * 256 + (ch - 256)];
        m = fmaxf(m, v);
    }
    part[((size_t)split * BB + b) * 512 + ch] = m;
}

__global__ void gmax_final(const float* __restrict__ part, float* __restrict__ xg) {
    int ch = threadIdx.x, b = blockIdx.x;
    float m = -INFINITY;
    for (int s = 0; s < NSPLIT; ++s) m = fmaxf(m, part[((size_t)s * BB + b) * 512 + ch]);
    xg[(size_t)b * 512 + ch] = m;
}

// ---------------- final linear + BN + lrelu ----------------
__global__ void linear_kernel(const float* __restrict__ xg, const float* __restrict__ lw,
    const float* __restrict__ lb, const float* __restrict__ g5, const float* __restrict__ b5,
    const float* __restrict__ rm5, const float* __restrict__ rv5, float* __restrict__ out0) {
    int o = blockIdx.x * 256 + threadIdx.x;
    int b = blockIdx.y;
    __shared__ float xs[512];
    for (int l = threadIdx.x; l < 512; l += 256) xs[l] = xg[(size_t)b * 512 + l];
    __syncthreads();
    float acc = 0.f;
    const float* wr = lw + (size_t)o * 512;
    for (int c = 0; c < 512; ++c) acc = fmaf(xs[c], wr[c], acc);
    acc += lb[o];
    float s = g5[o] * rsqrtf(rv5[o] + EPSF);
    float h = fmaf(s, acc - rm5[o], b5[o]);
    out0[(size_t)b * 1024 + o] = (h >= 0.f) ? h : NEG_SLOPE * h;
}

// ---------------- x4 (B,N,256) -> out1 (B,256,N) ----------------
__global__ void transpose_kernel(const float* __restrict__ x4, float* __restrict__ out1) {
    __shared__ float tile[32][33];
    int b = blockIdx.z;
    int nb = blockIdx.x * 32, ob = blockIdx.y * 32;
    int tx = threadIdx.x, ty = threadIdx.y;  // (32, 8)
    #pragma unroll
    for (int r = 0; r < 4; ++r) {
        int o = ob + tx;
        int n = nb + ty + r * 8;
        tile[ty + r * 8][tx] = x4[((size_t)b * NN + n) * 256 + o];
    }
    __syncthreads();
    #pragma unroll
    for (int r = 0; r < 4; ++r) {
        int n = nb + tx;
        int o = ob + ty + r * 8;
        out1[((size_t)b * 256 + o) * NN + n] = tile[tx][ty + r * 8];
    }
}

extern "C" void kernel_launch(void* const* d_in, const int* in_sizes, int n_in,
                              void* d_out, int out_size, void* d_ws, size_t ws_size,
                              hipStream_t stream) {
    const float* x = (const float*)d_in[0];
    const float* lin_w = (const float*)d_in[21];
    const float* lin_b = (const float*)d_in[22];
    const float* g5 = (const float*)d_in[23];
    const float* b5 = (const float*)d_in[24];
    const float* rm5 = (const float*)d_in[25];
    const float* rv5 = (const float*)d_in[26];

    // ---- workspace bump allocation ----
    size_t off = 0;
    auto alloc = [&](size_t nbytes) {
        void* r = (char*)d_ws + off;
        off += (nbytes + 255) & ~(size_t)255;
        return r;
    };
    const size_t PTS = (size_t)BB * NN;
    float* xx   = (float*)alloc(PTS * 4);
    int*   idx  = (int*)  alloc(PTS * KK * 4);
    float* y    = (float*)alloc(PTS * 256 * 4);
    float* z    = (float*)alloc(PTS * 256 * 4);
    float* x1   = (float*)alloc(PTS * 64 * 4);
    float* x2   = (float*)alloc(PTS * 64 * 4);
    float* x3   = (float*)alloc(PTS * 128 * 4);
    float* x4   = (float*)alloc(PTS * 256 * 4);
    float* part = (float*)alloc((size_t)NSPLIT * BB * 512 * 4);
    float* xg   = (float*)alloc((size_t)BB * 512 * 4);
    float* pv   = (float*)alloc((size_t)NSTRIP * PTS * KK * 4);  // per-strip top-10 values
    int*   pjb  = (int*)  alloc((size_t)NSTRIP * PTS * KK * 4);  // per-strip top-10 indices

    const int CI[4] = {5, 64, 64, 128};
    const int CO[4] = {64, 64, 128, 256};
    const float* xin = x;
    float* xout[4] = {x1, x2, x3, x4};

    for (int l = 0; l < 4; ++l) {
        int C = CI[l], co = CO[l];
        const float* w  = (const float*)d_in[1 + l * 5 + 0];
        const float* g  = (const float*)d_in[1 + l * 5 + 1];
        const float* be = (const float*)d_in[1 + l * 5 + 2];
        const float* rm = (const float*)d_in[1 + l * 5 + 3];
        const float* rv = (const float*)d_in[1 + l * 5 + 4];

        xx_kernel<<<(BB * NN + 255) / 256, 256, 0, stream>>>(xin, xx, C);

        dim3 dgrid(NN / 64, BB, NSTRIP);
        if (C == 5)
            dist_topk_kernel<5><<<dgrid, 256, 0, stream>>>(xin, xx, pv, pjb);
        else if (C == 64)
            dist_topk_kernel<64><<<dgrid, 256, 0, stream>>>(xin, xx, pv, pjb);
        else
            dist_topk_kernel<128><<<dgrid, 256, 0, stream>>>(xin, xx, pv, pjb);
        topk_merge_kernel<<<(int)((PTS + 255) / 256), 256, 0, stream>>>(pv, pjb, idx);

        yz_gemm_kernel<<<dim3(2 * co / 64, (int)(PTS / 64)), 256, 0, stream>>>(
            xin, w, y, z, C, co);
        edge_apply_kernel<<<(int)PTS, co, 0, stream>>>(y, z, idx, g, be, rm, rv, xout[l], co);
        xin = xout[l];
    }

    gmax_partial<<<dim3(NSPLIT, BB), 512, 0, stream>>>(x1, x2, x3, x4, part);
    gmax_final<<<BB, 512, 0, stream>>>(part, xg);
    linear_kernel<<<dim3(1024 / 256, BB), 256, 0, stream>>>(
        xg, lin_w, lin_b, g5, b5, rm5, rv5, (float*)d_out);
    transpose_kernel<<<dim3(NN / 32, 256 / 32, BB), dim3(32, 8), 0, stream>>>(
        x4, (float*)d_out + (size_t)BB * 1024);
}